// Round 5
// baseline (313.604 us; speedup 1.0000x reference)
//
#include <hip/hip_runtime.h>
#include <stdint.h>

#define B 8
#define L 4096
#define C 1024
#define H 512
#define CCH 64
#define NPART 512            // one partial per block (64 rows each)

// ---- K_A: fused t1 + exp + weighted accumulate, single pass over x ----
// 512 blocks; block handles 64 rows of one batch; wave handles 16 rows;
// lane holds 16 cols (float4 at col4 = lane + 64k). Block-level LDS reduce
// -> one 4 KB partial per block. Also zeroes MLP atomic targets (blocks<48).
__global__ __launch_bounds__(256) void kA_fused(const float* __restrict__ x,
                                                const float* __restrict__ w1,
                                                const float* __restrict__ b1,
                                                float* __restrict__ partial_xa,
                                                float* __restrict__ partial_s,
                                                float* __restrict__ zero_targets) {
    __shared__ float4 lds[4][256];
    __shared__ float ldsS[4];
    int t = threadIdx.x;
    int wave = t >> 6, lane = t & 63;
    int b = blockIdx.x >> 6;
    int blkInB = blockIdx.x & 63;
    int l0 = blkInB * 64 + wave * 16;
    float b1v = b1[0];

    if (blockIdx.x < 48) zero_targets[blockIdx.x * 256 + t] = 0.f;  // 12288 floats

    const float4* w1v = (const float4*)w1;
    float4 wf[4];
#pragma unroll
    for (int k = 0; k < 4; ++k) wf[k] = w1v[lane + 64 * k];

    float4 acc[4];
#pragma unroll
    for (int k = 0; k < 4; ++k) acc[k] = make_float4(0.f, 0.f, 0.f, 0.f);
    float sexp = 0.f;

    for (int r = 0; r < 16; ++r) {
        const float4* row = (const float4*)(x + ((size_t)(b * L + l0 + r)) * C);
        float4 xv[4];
#pragma unroll
        for (int k = 0; k < 4; ++k) xv[k] = row[lane + 64 * k];
        float d = 0.f;
#pragma unroll
        for (int k = 0; k < 4; ++k)
            d += xv[k].x * wf[k].x + xv[k].y * wf[k].y + xv[k].z * wf[k].z + xv[k].w * wf[k].w;
#pragma unroll
        for (int off = 32; off > 0; off >>= 1) d += __shfl_xor(d, off, 64);
        float e = __expf(d + b1v);   // |t1| ~ O(3): safe without max subtraction
        sexp += e;
#pragma unroll
        for (int k = 0; k < 4; ++k) {
            acc[k].x += e * xv[k].x;
            acc[k].y += e * xv[k].y;
            acc[k].z += e * xv[k].z;
            acc[k].w += e * xv[k].w;
        }
    }
#pragma unroll
    for (int k = 0; k < 4; ++k) lds[wave][lane + 64 * k] = acc[k];
    if (lane == 0) ldsS[wave] = sexp;
    __syncthreads();
    // thread t owns float4-column t
    float4 s0 = lds[0][t], s1 = lds[1][t], s2 = lds[2][t], s3 = lds[3][t];
    float4 s4;
    s4.x = (s0.x + s1.x) + (s2.x + s3.x);
    s4.y = (s0.y + s1.y) + (s2.y + s3.y);
    s4.z = (s0.z + s1.z) + (s2.z + s3.z);
    s4.w = (s0.w + s1.w) + (s2.w + s3.w);
    ((float4*)partial_xa)[(size_t)blockIdx.x * 256 + t] = s4;
    if (t == 0) partial_s[blockIdx.x] = (ldsS[0] + ldsS[1]) + (ldsS[2] + ldsS[3]);
}

// ---- k4a: reduce partials -> normalized xa slice; GEMV w2 -> pooled ---
// grid 32: hg = blk&1 (h half of 256), cc = blk>>1 (c chunk of 64)
__global__ __launch_bounds__(256) void k4a_pooled(const float* __restrict__ partial_xa,
                                                  const float* __restrict__ partial_s,
                                                  const float* __restrict__ w2,
                                                  const float* __restrict__ b2,
                                                  float* __restrict__ pooled) {
    __shared__ float ldsS[512];
    __shared__ float invS[B];
    __shared__ float xs[B][CCH];
    int hg = blockIdx.x & 1;
    int cc = blockIdx.x >> 1;
    int c0 = cc * CCH;
    int t = threadIdx.x;

    ldsS[t] = partial_s[t];
    ldsS[t + 256] = partial_s[t + 256];
    __syncthreads();
    if (t < B) {
        float s = 0.f;
        for (int i = 0; i < 64; ++i) s += ldsS[t * 64 + i];
        invS[t] = 1.f / s;
    }
    __syncthreads();

    // reduce 64 partials per batch for the 64-col slice; 2 entries per thread
#pragma unroll
    for (int p = 0; p < 2; ++p) {
        int e = t + p * 256;
        int bb = e >> 6, ci = e & 63;
        float s = 0.f;
        const float* src = partial_xa + (size_t)(bb * 64) * C + c0 + ci;
        for (int j = 0; j < 64; ++j) s += src[(size_t)j * C];
        xs[bb][ci] = s * invS[bb];
    }
    __syncthreads();

    int h = hg * 256 + t;
    float acc[B] = {0.f, 0.f, 0.f, 0.f, 0.f, 0.f, 0.f, 0.f};
#pragma unroll 4
    for (int ci = 0; ci < CCH; ++ci) {
        float w = w2[(size_t)(c0 + ci) * H + h];
#pragma unroll
        for (int bb = 0; bb < B; ++bb) acc[bb] += xs[bb][ci] * w;
    }
    float bias = (cc == 0) ? b2[h] : 0.f;
#pragma unroll
    for (int bb = 0; bb < B; ++bb) atomicAdd(&pooled[bb * H + h], acc[bb] + bias);
}

// ---- k4bc: fused v-compute (from pooled) + u4/u5 accumulation ---------
// grid 32: hg = blk&1 (h half), cc = blk>>1 (c chunk of 64)
__global__ __launch_bounds__(256) void k4bc(const float* __restrict__ pooled,
                                            const float* __restrict__ w3,
                                            const float* __restrict__ b3,
                                            const float* __restrict__ w4,
                                            const float* __restrict__ w5,
                                            float* __restrict__ u4raw,
                                            float* __restrict__ u5raw) {
    __shared__ float pooledS[B][H];      // 16 KB
    __shared__ float vpart[4][B][CCH];   // 8 KB
    __shared__ float vs[B][CCH];         // 2 KB
    int hg = blockIdx.x & 1;
    int cc = blockIdx.x >> 1;
    int c0 = cc * CCH;
    int t = threadIdx.x;

    for (int i = t; i < B * H; i += 256) ((float*)pooledS)[i] = pooled[i];
    __syncthreads();

    {   // stage 1: vraw slice (split h into 4 quarters across thread groups)
        int ci = t & 63;
        int hq = t >> 6;
        float a[B] = {0.f, 0.f, 0.f, 0.f, 0.f, 0.f, 0.f, 0.f};
        for (int hh = 0; hh < 128; ++hh) {
            int h = hq * 128 + hh;
            float w = w3[(size_t)h * C + c0 + ci];
#pragma unroll
            for (int bb = 0; bb < B; ++bb) a[bb] += pooledS[bb][h] * w;
        }
#pragma unroll
        for (int bb = 0; bb < B; ++bb) vpart[hq][bb][ci] = a[bb];
    }
    __syncthreads();
#pragma unroll
    for (int p = 0; p < 2; ++p) {  // combine quarters + bias + sigmoid
        int idx = t * 2 + p;
        int bb = idx >> 6, ci = idx & 63;
        float v = vpart[0][bb][ci] + vpart[1][bb][ci] + vpart[2][bb][ci] + vpart[3][bb][ci]
                + b3[c0 + ci];
        vs[bb][ci] = 1.f / (1.f + __expf(-v));
    }
    __syncthreads();
    {   // stage 2: u4/u5 accumulation
        int h = hg * 256 + t;
        float a4[B] = {0.f, 0.f, 0.f, 0.f, 0.f, 0.f, 0.f, 0.f};
        float a5[B] = {0.f, 0.f, 0.f, 0.f, 0.f, 0.f, 0.f, 0.f};
#pragma unroll 2
        for (int ci = 0; ci < CCH; ++ci) {
            float wa = w4[(size_t)(c0 + ci) * H + h];
            float wb = w5[(size_t)(c0 + ci) * H + h];
#pragma unroll
            for (int bb = 0; bb < B; ++bb) {
                a4[bb] += vs[bb][ci] * wa;
                a5[bb] += vs[bb][ci] * wb;
            }
        }
#pragma unroll
        for (int bb = 0; bb < B; ++bb) {
            atomicAdd(&u4raw[bb * H + h], a4[bb]);
            atomicAdd(&u5raw[bb * H + h], a5[bb]);
        }
    }
}

// ---- k5: per-block redundant scal[b] dot + fill its 64 KB region ------
// grid 2048: b = blk>>8, region = blk&255 (16384 floats each)
__global__ __launch_bounds__(256) void k5_fill(const float* __restrict__ u4raw, const float* __restrict__ b4,
                                               const float* __restrict__ u5raw, const float* __restrict__ b5,
                                               float* __restrict__ out) {
    __shared__ float red[256];
    int blk = blockIdx.x, t = threadIdx.x;
    int b = blk >> 8;
    int rg = blk & 255;
    float s = (u4raw[b * H + t] + b4[t]) * (u5raw[b * H + t] + b5[t])
            + (u4raw[b * H + 256 + t] + b4[256 + t]) * (u5raw[b * H + 256 + t] + b5[256 + t]);
    red[t] = s; __syncthreads();
    for (int st = 128; st > 0; st >>= 1) { if (t < st) red[t] += red[t + st]; __syncthreads(); }
    float sc = 1.f / (1.f + __expf(-red[0]));
    float4 s4 = make_float4(sc, sc, sc, sc);
    float4* o = (float4*)out + (size_t)b * (L * C / 4) + (size_t)rg * 4096;
#pragma unroll
    for (int k = 0; k < 16; ++k) o[t + 256 * k] = s4;
}

extern "C" void kernel_launch(void* const* d_in, const int* in_sizes, int n_in,
                              void* d_out, int out_size, void* d_ws, size_t ws_size,
                              hipStream_t stream) {
    const float* x  = (const float*)d_in[0];
    const float* w1 = (const float*)d_in[1];
    const float* b1 = (const float*)d_in[2];
    const float* w2 = (const float*)d_in[3];
    const float* b2 = (const float*)d_in[4];
    const float* w3 = (const float*)d_in[5];
    const float* b3 = (const float*)d_in[6];
    const float* w4 = (const float*)d_in[7];
    const float* b4 = (const float*)d_in[8];
    const float* w5 = (const float*)d_in[9];
    const float* b5 = (const float*)d_in[10];

    float* ws         = (float*)d_ws;
    float* partial_xa = ws;                          // NPART*C = 512K floats (2 MB)
    float* partial_s  = partial_xa + NPART * C;      // 512
    float* pooled     = partial_s + NPART;           // B*H = 4096   } contiguous
    float* u4raw      = pooled + B * H;              // B*H = 4096   } zero block
    float* u5raw      = u4raw + B * H;               // B*H = 4096   } (12288 floats)

    kA_fused<<<NPART, 256, 0, stream>>>(x, w1, b1, partial_xa, partial_s, pooled);
    k4a_pooled<<<32, 256, 0, stream>>>(partial_xa, partial_s, w2, b2, pooled);
    k4bc<<<32, 256, 0, stream>>>(pooled, w3, b3, w4, w5, u4raw, u5raw);
    k5_fill<<<2048, 256, 0, stream>>>(u4raw, b4, u5raw, b5, (float*)d_out);
}

// Round 6
// 281.674 us; speedup vs baseline: 1.1134x; 1.1134x over previous
//
#include <hip/hip_runtime.h>
#include <stdint.h>

#define B 8
#define L 4096
#define C 1024
#define H 512
#define NPART 512            // one partial per kA block (64 rows each)
#define CCH 16               // c-chunk for MLP kernels (128 blocks each)

// ---- K_A: fused t1 + exp + weighted accumulate, single pass over x ----
// 512 blocks; block handles 64 rows of one batch; wave handles 16 rows;
// lane holds 16 cols (float4 at col4 = lane + 64k). Block-level LDS reduce
// -> one 4 KB partial per block. Also zeroes MLP atomic targets (blocks<48).
__global__ __launch_bounds__(256) void kA_fused(const float* __restrict__ x,
                                                const float* __restrict__ w1,
                                                const float* __restrict__ b1,
                                                float* __restrict__ partial_xa,
                                                float* __restrict__ partial_s,
                                                float* __restrict__ zero_targets) {
    __shared__ float4 lds[4][256];
    __shared__ float ldsS[4];
    int t = threadIdx.x;
    int wave = t >> 6, lane = t & 63;
    int b = blockIdx.x >> 6;
    int blkInB = blockIdx.x & 63;
    int l0 = blkInB * 64 + wave * 16;
    float b1v = b1[0];

    if (blockIdx.x < 48) zero_targets[blockIdx.x * 256 + t] = 0.f;  // 12288 floats

    const float4* w1v = (const float4*)w1;
    float4 wf[4];
#pragma unroll
    for (int k = 0; k < 4; ++k) wf[k] = w1v[lane + 64 * k];

    float4 acc[4];
#pragma unroll
    for (int k = 0; k < 4; ++k) acc[k] = make_float4(0.f, 0.f, 0.f, 0.f);
    float sexp = 0.f;

    for (int r = 0; r < 16; ++r) {
        const float4* row = (const float4*)(x + ((size_t)(b * L + l0 + r)) * C);
        float4 xv[4];
#pragma unroll
        for (int k = 0; k < 4; ++k) xv[k] = row[lane + 64 * k];
        float d = 0.f;
#pragma unroll
        for (int k = 0; k < 4; ++k)
            d += xv[k].x * wf[k].x + xv[k].y * wf[k].y + xv[k].z * wf[k].z + xv[k].w * wf[k].w;
#pragma unroll
        for (int off = 32; off > 0; off >>= 1) d += __shfl_xor(d, off, 64);
        float e = __expf(d + b1v);   // |t1| ~ O(3): safe without max subtraction
        sexp += e;
#pragma unroll
        for (int k = 0; k < 4; ++k) {
            acc[k].x += e * xv[k].x;
            acc[k].y += e * xv[k].y;
            acc[k].z += e * xv[k].z;
            acc[k].w += e * xv[k].w;
        }
    }
#pragma unroll
    for (int k = 0; k < 4; ++k) lds[wave][lane + 64 * k] = acc[k];
    if (lane == 0) ldsS[wave] = sexp;
    __syncthreads();
    float4 s0 = lds[0][t], s1 = lds[1][t], s2 = lds[2][t], s3 = lds[3][t];
    float4 s4;
    s4.x = (s0.x + s1.x) + (s2.x + s3.x);
    s4.y = (s0.y + s1.y) + (s2.y + s3.y);
    s4.z = (s0.z + s1.z) + (s2.z + s3.z);
    s4.w = (s0.w + s1.w) + (s2.w + s3.w);
    ((float4*)partial_xa)[(size_t)blockIdx.x * 256 + t] = s4;
    if (t == 0) partial_s[blockIdx.x] = (ldsS[0] + ldsS[1]) + (ldsS[2] + ldsS[3]);
}

// ---- k4a: reduce partials -> normalized xa slice; GEMV w2 -> pooled ---
// grid 128: hg = blk&1 (h half of 256), cc = blk>>1 (c chunk of 16)
__global__ __launch_bounds__(256) void k4a_pooled(const float* __restrict__ partial_xa,
                                                  const float* __restrict__ partial_s,
                                                  const float* __restrict__ w2,
                                                  const float* __restrict__ b2,
                                                  float* __restrict__ pooled) {
    __shared__ float ldsS[512];
    __shared__ float invS[B];
    __shared__ float xs[B][CCH];
    int hg = blockIdx.x & 1;
    int cc = blockIdx.x >> 1;          // 0..63
    int c0 = cc * CCH;
    int t = threadIdx.x;

    ldsS[t] = partial_s[t];
    ldsS[t + 256] = partial_s[t + 256];
    __syncthreads();
    if (t < B) {
        float s = 0.f;
        for (int i = 0; i < 64; ++i) s += ldsS[t * 64 + i];
        invS[t] = 1.f / s;
    }
    __syncthreads();

    // reduce 64 partials per batch for the 16-col slice; B*CCH = 128 entries
    if (t < B * CCH) {
        int bb = t >> 4, ci = t & 15;
        float s = 0.f;
        const float* src = partial_xa + (size_t)(bb * 64) * C + c0 + ci;
        for (int j = 0; j < 64; ++j) s += src[(size_t)j * C];
        xs[bb][ci] = s * invS[bb];
    }
    __syncthreads();

    int h = hg * 256 + t;
    float acc[B] = {0.f, 0.f, 0.f, 0.f, 0.f, 0.f, 0.f, 0.f};
#pragma unroll
    for (int ci = 0; ci < CCH; ++ci) {
        float w = w2[(size_t)(c0 + ci) * H + h];
#pragma unroll
        for (int bb = 0; bb < B; ++bb) acc[bb] += xs[bb][ci] * w;
    }
    float bias = (cc == 0) ? b2[h] : 0.f;
#pragma unroll
    for (int bb = 0; bb < B; ++bb) atomicAdd(&pooled[bb * H + h], acc[bb] + bias);
}

// ---- k4bc: fused v-compute (from pooled) + u4/u5 accumulation ---------
// grid 128: hg = blk&1 (h half), cc = blk>>1 (c chunk of 16)
__global__ __launch_bounds__(256) void k4bc(const float* __restrict__ pooled,
                                            const float* __restrict__ w3,
                                            const float* __restrict__ b3,
                                            const float* __restrict__ w4,
                                            const float* __restrict__ w5,
                                            float* __restrict__ u4raw,
                                            float* __restrict__ u5raw) {
    __shared__ float pooledS[B][H];         // 16 KB
    __shared__ float vpart[16][B][CCH];     // 8 KB: 16 h-quarters of 32 h
    __shared__ float vs[B][CCH];            // 512 B
    int hg = blockIdx.x & 1;
    int cc = blockIdx.x >> 1;               // 0..63
    int c0 = cc * CCH;
    int t = threadIdx.x;

    for (int i = t; i < B * H; i += 256) ((float*)pooledS)[i] = pooled[i];
    __syncthreads();

    {   // stage 1: vraw slice; thread group hq covers 32 h values
        int ci = t & 15;
        int hq = t >> 4;                    // 0..15
        float a[B] = {0.f, 0.f, 0.f, 0.f, 0.f, 0.f, 0.f, 0.f};
        for (int hh = 0; hh < 32; ++hh) {
            int h = hq * 32 + hh;
            float w = w3[(size_t)h * C + c0 + ci];
#pragma unroll
            for (int bb = 0; bb < B; ++bb) a[bb] += pooledS[bb][h] * w;
        }
#pragma unroll
        for (int bb = 0; bb < B; ++bb) vpart[hq][bb][ci] = a[bb];
    }
    __syncthreads();
    if (t < B * CCH) {  // combine quarters + bias + sigmoid (128 values)
        int bb = t >> 4, ci = t & 15;
        float v = b3[c0 + ci];
#pragma unroll
        for (int q = 0; q < 16; ++q) v += vpart[q][bb][ci];
        vs[bb][ci] = 1.f / (1.f + __expf(-v));
    }
    __syncthreads();
    {   // stage 2: u4/u5 accumulation
        int h = hg * 256 + t;
        float a4[B] = {0.f, 0.f, 0.f, 0.f, 0.f, 0.f, 0.f, 0.f};
        float a5[B] = {0.f, 0.f, 0.f, 0.f, 0.f, 0.f, 0.f, 0.f};
#pragma unroll
        for (int ci = 0; ci < CCH; ++ci) {
            float wa = w4[(size_t)(c0 + ci) * H + h];
            float wb = w5[(size_t)(c0 + ci) * H + h];
#pragma unroll
            for (int bb = 0; bb < B; ++bb) {
                a4[bb] += vs[bb][ci] * wa;
                a5[bb] += vs[bb][ci] * wb;
            }
        }
#pragma unroll
        for (int bb = 0; bb < B; ++bb) {
            atomicAdd(&u4raw[bb * H + h], a4[bb]);
            atomicAdd(&u5raw[bb * H + h], a5[bb]);
        }
    }
}

// ---- k5: per-block redundant scal[b] dot + fill its 64 KB region ------
// grid 2048: b = blk>>8, region = blk&255 (16384 floats each)
__global__ __launch_bounds__(256) void k5_fill(const float* __restrict__ u4raw, const float* __restrict__ b4,
                                               const float* __restrict__ u5raw, const float* __restrict__ b5,
                                               float* __restrict__ out) {
    __shared__ float red[256];
    int blk = blockIdx.x, t = threadIdx.x;
    int b = blk >> 8;
    int rg = blk & 255;
    float s = (u4raw[b * H + t] + b4[t]) * (u5raw[b * H + t] + b5[t])
            + (u4raw[b * H + 256 + t] + b4[256 + t]) * (u5raw[b * H + 256 + t] + b5[256 + t]);
    red[t] = s; __syncthreads();
    for (int st = 128; st > 0; st >>= 1) { if (t < st) red[t] += red[t + st]; __syncthreads(); }
    float sc = 1.f / (1.f + __expf(-red[0]));
    float4 s4 = make_float4(sc, sc, sc, sc);
    float4* o = (float4*)out + (size_t)b * (L * C / 4) + (size_t)rg * 4096;
#pragma unroll
    for (int k = 0; k < 16; ++k) o[t + 256 * k] = s4;
}

extern "C" void kernel_launch(void* const* d_in, const int* in_sizes, int n_in,
                              void* d_out, int out_size, void* d_ws, size_t ws_size,
                              hipStream_t stream) {
    const float* x  = (const float*)d_in[0];
    const float* w1 = (const float*)d_in[1];
    const float* b1 = (const float*)d_in[2];
    const float* w2 = (const float*)d_in[3];
    const float* b2 = (const float*)d_in[4];
    const float* w3 = (const float*)d_in[5];
    const float* b3 = (const float*)d_in[6];
    const float* w4 = (const float*)d_in[7];
    const float* b4 = (const float*)d_in[8];
    const float* w5 = (const float*)d_in[9];
    const float* b5 = (const float*)d_in[10];

    float* ws         = (float*)d_ws;
    float* partial_xa = ws;                          // NPART*C = 512K floats (2 MB)
    float* partial_s  = partial_xa + NPART * C;      // 512
    float* pooled     = partial_s + NPART;           // B*H = 4096   } contiguous
    float* u4raw      = pooled + B * H;              // B*H = 4096   } zero block
    float* u5raw      = u4raw + B * H;               // B*H = 4096   } (12288 floats)

    kA_fused<<<NPART, 256, 0, stream>>>(x, w1, b1, partial_xa, partial_s, pooled);
    k4a_pooled<<<128, 256, 0, stream>>>(partial_xa, partial_s, w2, b2, pooled);
    k4bc<<<128, 256, 0, stream>>>(pooled, w3, b3, w4, w5, u4raw, u5raw);
    k5_fill<<<2048, 256, 0, stream>>>(u4raw, b4, u5raw, b5, (float*)d_out);
}